// Round 21
// baseline (118.017 us; speedup 1.0000x reference)
//
#include <hip/hip_runtime.h>
#include <hip/hip_bf16.h>

#define DIM 1024
#define NHEADS 16
#define HD 64
#define SEQ 2048
#define BATCH 2
#define MROWS (BATCH * SEQ)   // 4096
#define MB (1024u * 1024u)
#define NT (SEQ / 64)         // 32 q-tiles

typedef __bf16 bf16x8 __attribute__((ext_vector_type(8)));
typedef float f32x4 __attribute__((ext_vector_type(4)));
typedef short short8 __attribute__((ext_vector_type(8)));

#define SCQ (0.125f * 1.44269504f)   // 1/sqrt(64) * log2(e), folded into Q

__device__ __forceinline__ unsigned short f2bf(float f) {
    union { float f; unsigned u; } v; v.f = f;
    unsigned r = v.u + 0x7fffu + ((v.u >> 16) & 1u);
    return (unsigned short)(r >> 16);
}
__device__ __forceinline__ float bf2f(unsigned short h) {
    union { unsigned u; float f; } v; v.u = ((unsigned)h) << 16;
    return v.f;
}
__device__ __forceinline__ unsigned cvtpk(float lo, float hi) {
    unsigned r;
    asm("v_cvt_pk_bf16_f32 %0, %1, %2" : "=v"(r) : "v"(lo), "v"(hi));
    return r;
}

// async global->LDS, 16B per lane; LDS dest = wave-uniform base + lane*16
__device__ __forceinline__ void gld16(const unsigned short* g, unsigned short* l) {
    __builtin_amdgcn_global_load_lds(
        (const __attribute__((address_space(1))) void*)g,
        (__attribute__((address_space(3))) void*)l, 16, 0, 0);
}

#define VWAIT(n) asm volatile("s_waitcnt vmcnt(" #n ")" ::: "memory")
#define BARRIER  do { __builtin_amdgcn_s_barrier(); __builtin_amdgcn_sched_barrier(0); } while (0)

// ---------------- fused fp32 -> bf16 conversion (x + 4 weights) ------------
__global__ __launch_bounds__(256) void f2all_kernel(
    const float* __restrict__ x,
    const float* __restrict__ w0, const float* __restrict__ w1,
    const float* __restrict__ w2, const float* __restrict__ w3,
    unsigned short* __restrict__ xb,
    unsigned short* __restrict__ o0, unsigned short* __restrict__ o1,
    unsigned short* __restrict__ o2, unsigned short* __restrict__ o3)
{
    const float* in; unsigned short* out; int n4;
    switch (blockIdx.y) {
        case 0: in = x;  out = xb; n4 = (MROWS * DIM) / 4; break;
        case 1: in = w0; out = o0; n4 = (DIM * DIM) / 4;   break;
        case 2: in = w1; out = o1; n4 = (DIM * DIM) / 4;   break;
        case 3: in = w2; out = o2; n4 = (DIM * DIM) / 4;   break;
        default: in = w3; out = o3; n4 = (DIM * DIM) / 4;  break;
    }
    for (int i = blockIdx.x * 256 + threadIdx.x; i < n4; i += 1024 * 256) {
        float4 v = ((const float4*)in)[i];
        ushort4 o;
        o.x = f2bf(v.x); o.y = f2bf(v.y); o.z = f2bf(v.z); o.w = f2bf(v.w);
        ((ushort4*)out)[i] = o;
    }
}

// ========== GEMM mainloop: 3-buffer, 2-deep counted-vmcnt pipeline ==========
#define GEMM_VARS(Aptr, Bptr)                                                  \
    __shared__ unsigned short As[3][128 * 32];                                 \
    __shared__ unsigned short Bs[3][128 * 32];                                 \
    const int tid  = threadIdx.x;                                              \
    const int lane = tid & 63;                                                 \
    const int wid  = tid >> 6;                                                 \
    const int wrow = wid >> 1, wcol = wid & 1;                                 \
    const int l15  = lane & 15;                                                \
    const int lhi  = lane >> 4;                                                \
    f32x4 acc[4][4] = {};                                                      \
    const int r0s = tid >> 2;                                                  \
    const int c0s = (tid & 3) ^ ((r0s >> 1) & 3);                              \
    const int r1s = (tid + 256) >> 2;                                          \
    const int c1s = (tid & 3) ^ ((r1s >> 1) & 3);                              \
    const unsigned short* gA0 = (Aptr) + (size_t)(row0 + r0s) * DIM + c0s * 8; \
    const unsigned short* gA1 = (Aptr) + (size_t)(row0 + r1s) * DIM + c1s * 8; \
    const unsigned short* gB0 = (Bptr) + (size_t)(col0 + r0s) * DIM + c0s * 8; \
    const unsigned short* gB1 = (Bptr) + (size_t)(col0 + r1s) * DIM + c1s * 8;

#define GEMM_STAGE(bi, kofs)                                                   \
    gld16(gA0 + (kofs), &As[bi][tid * 8]);                                     \
    gld16(gA1 + (kofs), &As[bi][(tid + 256) * 8]);                             \
    gld16(gB0 + (kofs), &Bs[bi][tid * 8]);                                     \
    gld16(gB1 + (kofs), &Bs[bi][(tid + 256) * 8]);

#define GEMM_COMPUTE(bi)                                                       \
    {   const unsigned short* Ac = &As[bi][0];                                 \
        const unsigned short* Bc = &Bs[bi][0];                                 \
        bf16x8 af[4], bfr[4];                                                  \
        _Pragma("unroll")                                                      \
        for (int m = 0; m < 4; m++) {                                          \
            int r = wrow * 64 + m * 16 + l15;                                  \
            int c = lhi ^ ((r >> 1) & 3);                                      \
            af[m] = *(const bf16x8*)&Ac[r * 32 + c * 8];                       \
        }                                                                      \
        _Pragma("unroll")                                                      \
        for (int n = 0; n < 4; n++) {                                          \
            int r = wcol * 64 + n * 16 + l15;                                  \
            int c = lhi ^ ((r >> 1) & 3);                                      \
            bfr[n] = *(const bf16x8*)&Bc[r * 32 + c * 8];                      \
        }                                                                      \
        __builtin_amdgcn_s_setprio(1);                                         \
        _Pragma("unroll")                                                      \
        for (int m = 0; m < 4; m++)                                            \
            _Pragma("unroll")                                                  \
            for (int n = 0; n < 4; n++)                                        \
                acc[m][n] = __builtin_amdgcn_mfma_f32_16x16x32_bf16(           \
                    af[m], bfr[n], acc[m][n], 0, 0, 0);                        \
        __builtin_amdgcn_s_setprio(0);                                         \
    }

#define GEMM_PIPELINE()                                                        \
    GEMM_STAGE(0, 0)                                                           \
    GEMM_STAGE(1, 32)                                                          \
    int bi = 0;                                                                \
    for (int k0 = 0; k0 + 96 <= DIM; k0 += 32) {                               \
        VWAIT(4);                                                              \
        BARRIER;                                                               \
        int b2 = bi + 2; if (b2 >= 3) b2 -= 3;                                 \
        GEMM_STAGE(b2, k0 + 64)                                                \
        GEMM_COMPUTE(bi)                                                       \
        bi = (bi + 1 == 3) ? 0 : bi + 1;                                       \
    }                                                                          \
    VWAIT(4);                                                                  \
    BARRIER;                                                                   \
    GEMM_COMPUTE(bi)                                                           \
    bi = (bi + 1 == 3) ? 0 : bi + 1;                                           \
    VWAIT(0);                                                                  \
    BARRIER;                                                                   \
    GEMM_COMPUTE(bi)

// ---------------- fused QKV GEMM (768 blocks, r10-proven XCD swizzle) ------
__global__ __launch_bounds__(256) void qkv_gemm(
    const unsigned short* __restrict__ A,
    const unsigned short* __restrict__ Wqb,
    const unsigned short* __restrict__ Wkb,
    const unsigned short* __restrict__ Wvb,
    unsigned short* __restrict__ Qb,
    unsigned short* __restrict__ Kbf,
    unsigned short* __restrict__ Vtb)
{
    const int lb  = ((int)blockIdx.x & 7) * 96 + ((int)blockIdx.x >> 3);
    const int xx  = lb % 24;
    const int yy  = lb / 24;
    const int sel = xx >> 3;
    const unsigned short* Bw = (sel == 0) ? Wqb : ((sel == 1) ? Wkb : Wvb);
    const int row0 = yy * 128;
    const int col0 = (xx & 7) * 128;

    GEMM_VARS(A, Bw)
    GEMM_PIPELINE()

    const int cr = lhi * 4;
    unsigned short* outRM = (sel == 0) ? Qb : Kbf;
    #pragma unroll
    for (int m = 0; m < 4; m++) {
        #pragma unroll
        for (int n = 0; n < 4; n++) {
            int gc = col0 + wcol * 64 + n * 16 + l15;
            if (sel < 2) {
                #pragma unroll
                for (int j2 = 0; j2 < 4; j2++) {
                    int gr = row0 + wrow * 64 + m * 16 + cr + j2;
                    float v = acc[m][n][j2];
                    if (sel == 0) v *= SCQ;   // fold softmax scale + log2e into Q
                    outRM[(size_t)gr * DIM + gc] = f2bf(v);
                }
            } else {
                // Vt scatter: 4 consecutive s -> one 8B store
                int gr0 = row0 + wrow * 64 + m * 16 + cr;
                int bb = gr0 >> 11, s0 = gr0 & 2047;
                int hh = gc >> 6,  d = gc & 63;
                ushort4 pv4;
                pv4.x = f2bf(acc[m][n][0]);
                pv4.y = f2bf(acc[m][n][1]);
                pv4.z = f2bf(acc[m][n][2]);
                pv4.w = f2bf(acc[m][n][3]);
                *(ushort4*)&Vtb[(((size_t)bb * NHEADS + hh) * HD + d) * SEQ + s0] = pv4;
            }
        }
    }
}

// ------------- O-projection GEMM: 64x64 tile, 1024 blocks (4/CU) -----------
__global__ __launch_bounds__(256) void o_gemm(
    const unsigned short* __restrict__ A,
    const unsigned short* __restrict__ Bw,
    float* __restrict__ Cp,
    const float* __restrict__ bias)
{
    __shared__ unsigned short As[3][64 * 32];
    __shared__ unsigned short Bs[3][64 * 32];

    const int lb  = ((int)blockIdx.x & 7) * 128 + ((int)blockIdx.x >> 3);
    const int xx  = lb % 16;
    const int yy  = lb / 16;
    const int row0 = yy * 64;
    const int col0 = xx * 64;

    const int tid  = threadIdx.x;
    const int lane = tid & 63;
    const int wid  = tid >> 6;
    const int wrow = wid >> 1, wcol = wid & 1;
    const int l15  = lane & 15;
    const int lhi  = lane >> 4;
    f32x4 acc[2][2] = {};

    const int r0s = tid >> 2;
    const int c0s = (tid & 3) ^ ((r0s >> 1) & 3);
    const unsigned short* gA0 = A  + (size_t)(row0 + r0s) * DIM + c0s * 8;
    const unsigned short* gB0 = Bw + (size_t)(col0 + r0s) * DIM + c0s * 8;

#define OSTAGE(bi, kofs)                                     \
    gld16(gA0 + (kofs), &As[bi][tid * 8]);                   \
    gld16(gB0 + (kofs), &Bs[bi][tid * 8]);

#define OCOMPUTE(bi)                                                           \
    {   const unsigned short* Ac = &As[bi][0];                                 \
        const unsigned short* Bc = &Bs[bi][0];                                 \
        bf16x8 af[2], bfr[2];                                                  \
        _Pragma("unroll")                                                      \
        for (int m = 0; m < 2; m++) {                                          \
            int r = wrow * 32 + m * 16 + l15;                                  \
            int c = lhi ^ ((r >> 1) & 3);                                      \
            af[m] = *(const bf16x8*)&Ac[r * 32 + c * 8];                       \
        }                                                                      \
        _Pragma("unroll")                                                      \
        for (int n = 0; n < 2; n++) {                                          \
            int r = wcol * 32 + n * 16 + l15;                                  \
            int c = lhi ^ ((r >> 1) & 3);                                      \
            bfr[n] = *(const bf16x8*)&Bc[r * 32 + c * 8];                      \
        }                                                                      \
        __builtin_amdgcn_s_setprio(1);                                         \
        _Pragma("unroll")                                                      \
        for (int m = 0; m < 2; m++)                                            \
            _Pragma("unroll")                                                  \
            for (int n = 0; n < 2; n++)                                        \
                acc[m][n] = __builtin_amdgcn_mfma_f32_16x16x32_bf16(           \
                    af[m], bfr[n], acc[m][n], 0, 0, 0);                        \
        __builtin_amdgcn_s_setprio(0);                                         \
    }

    OSTAGE(0, 0)
    OSTAGE(1, 32)
    int bi = 0;
    for (int k0 = 0; k0 + 96 <= DIM; k0 += 32) {
        VWAIT(2);
        BARRIER;
        int b2 = bi + 2; if (b2 >= 3) b2 -= 3;
        OSTAGE(b2, k0 + 64)
        OCOMPUTE(bi)
        bi = (bi + 1 == 3) ? 0 : bi + 1;
    }
    VWAIT(2);
    BARRIER;
    OCOMPUTE(bi)
    bi = (bi + 1 == 3) ? 0 : bi + 1;
    VWAIT(0);
    BARRIER;
    OCOMPUTE(bi)
#undef OSTAGE
#undef OCOMPUTE

    const int cr = lhi * 4;
    #pragma unroll
    for (int m = 0; m < 2; m++) {
        #pragma unroll
        for (int n = 0; n < 2; n++) {
            #pragma unroll
            for (int j = 0; j < 4; j++) {
                int gr = row0 + wrow * 32 + m * 16 + cr + j;
                int gc = col0 + wcol * 32 + n * 16 + l15;
                Cp[(size_t)gr * DIM + gc] = acc[m][n][j] + bias[gc];
            }
        }
    }
}

// ---------------- causal flash attention (KV-split heavy pairs) ------------
// 768 blocks (3/CU with 50KB LDS). Heavy pairs (p=8..15) are split into TWO
// blocks over the KV range ([0,p+1) and [p+1,2p+2)) -- partials are additive
// because softmax uses a fixed max (no running-max merge). Heavy blocks write
// unnormalized bf16 partials + f32 sums; combine_kernel merges. Light pairs
// (p=0..7) write normalized output directly. Inner loop identical to r20.
#define ATTN_CORE(bi, t, MASKED)                                               \
    {   const unsigned short* Kc = &Ks[bi][0];                                 \
        const unsigned short* Vc = &Vs[bi][0];                                 \
        f32x4 sacc[4] = {};                                                    \
        __builtin_amdgcn_s_setprio(1);                                         \
        _Pragma("unroll")                                                      \
        for (int ks = 0; ks < 2; ++ks) {                                       \
            bf16x8 bq = ks ? aq1 : aq0;                                        \
            _Pragma("unroll")                                                  \
            for (int nt = 0; nt < 4; nt++) {                                   \
                int r = nt * 16 + l15;                                         \
                int c = (ks * 4 + lhi) ^ (r & 7);                              \
                bf16x8 ak = *(const bf16x8*)&Kc[r * 64 + c * 8];               \
                sacc[nt] = __builtin_amdgcn_mfma_f32_16x16x32_bf16(            \
                    ak, bq, sacc[nt], 0, 0, 0);                                \
            }                                                                  \
        }                                                                      \
        __builtin_amdgcn_s_setprio(0);                                         \
        _Pragma("unroll")                                                      \
        for (int nt = 0; nt < 4; nt++) {                                       \
            float pv[4];                                                       \
            _Pragma("unroll")                                                  \
            for (int j = 0; j < 4; j++) {                                      \
                if (MASKED && (nt * 16 + lhi * 4 + j > (w & 3) * 16 + l15))    \
                    pv[j] = 0.f;                                               \
                else                                                           \
                    pv[j] = exp2f(sacc[nt][j]);                                \
            }                                                                  \
            *(uint2*)&Ps[w][l15][nt * 16 + lhi * 4] =                          \
                make_uint2(cvtpk(pv[0], pv[1]), cvtpk(pv[2], pv[3]));          \
        }                                                                      \
        bf16x8 bv[2][4];                                                       \
        _Pragma("unroll")                                                      \
        for (int ks = 0; ks < 2; ++ks)                                         \
            _Pragma("unroll")                                                  \
            for (int dt = 0; dt < 4; dt++) {                                   \
                int r = dt * 16 + l15;                                         \
                int c = (ks * 4 + lhi) ^ (r & 7);                              \
                bv[ks][dt] = *(const bf16x8*)&Vc[r * 64 + c * 8];              \
            }                                                                  \
        _Pragma("unroll")                                                      \
        for (int ks = 0; ks < 2; ++ks) {                                       \
            bf16x8 ap = *(const bf16x8*)&Ps[w][l15][ks * 32 + lhi * 8];        \
            __builtin_amdgcn_s_setprio(1);                                     \
            _Pragma("unroll")                                                  \
            for (int dt = 0; dt < 4; dt++)                                     \
                octx[dt] = __builtin_amdgcn_mfma_f32_16x16x32_bf16(            \
                    ap, bv[ks][dt], octx[dt], 0, 0, 0);                        \
            octxS = __builtin_amdgcn_mfma_f32_16x16x32_bf16(ap, vones, octxS, 0, 0, 0); \
            __builtin_amdgcn_s_setprio(0);                                     \
        }                                                                      \
    }

__global__ __launch_bounds__(512) void attn_kernel(
    const unsigned short* __restrict__ Q,
    const unsigned short* __restrict__ Kb,
    const unsigned short* __restrict__ Vt,
    unsigned short* __restrict__ Ctx,
    unsigned short* __restrict__ pb,   // partials: [half][b][h][p-8][lr][64] bf16
    float* __restrict__ sb)            // sums:     [half][b][h][p-8][lr] f32
{
    __shared__ unsigned short Ks[2][64 * 64];
    __shared__ unsigned short Vs[2][64 * 64];
    __shared__ unsigned short Ps[8][16][72];

    const int tid  = threadIdx.x;
    const int lane = tid & 63;
    const int w    = tid >> 6;        // 0..7
    const int bid  = (int)blockIdx.x;
    // blocks 0-511: heavy halves (p=15 first); 512-767: light (p=7 first)
    const bool heavy = (bid < 512);
    int half, p, h, b;
    if (heavy) {
        int hp = bid >> 1; half = bid & 1;
        h = hp & 15; b = (hp >> 4) & 1; p = 15 - (hp >> 5);
    } else {
        int idx = bid - 512; half = 0;
        h = idx & 15; b = (idx >> 4) & 1; p = 7 - (idx >> 5);
    }
    const int lo = (heavy && half) ? (p + 1) : 0;
    const int hi = (heavy && !half) ? (p + 1) : (2 * p + 2);
    const int l15  = lane & 15;
    const int lhi  = lane >> 4;

    const int qblk = 2 * p + (w >> 2);     // waves 0-3: 2p, waves 4-7: 2p+1
    const int qw   = qblk * 64 + (w & 3) * 16;

    const size_t qrow = ((size_t)b * SEQ + qw + l15) * DIM + h * HD;
    bf16x8 aq0 = *(const bf16x8*)(Q + qrow + lhi * 8);
    bf16x8 aq1 = *(const bf16x8*)(Q + qrow + 32 + lhi * 8);

    const int srow = tid >> 3;                   // 0..63
    const int sc16 = (tid & 7) ^ (srow & 7);
    const unsigned short* gK = Kb + ((size_t)b * SEQ + srow) * DIM + h * HD + sc16 * 8;
    const unsigned short* gV = Vt + (((size_t)b * NHEADS + h) * HD + srow) * SEQ + sc16 * 8;

    bf16x8 vones;
    #pragma unroll
    for (int i = 0; i < 8; i++) vones[i] = (__bf16)1.0f;

    f32x4 octx[4] = {};
    f32x4 octxS = {};

    gld16(gK + (size_t)lo * 64 * DIM, &Ks[0][tid * 8]);
    gld16(gV + (size_t)lo * 64,       &Vs[0][tid * 8]);
    VWAIT(0);
    BARRIER;

    int cur = 0;
    for (int t = lo; t < hi; ++t) {
        if (t + 1 < hi) {
            gld16(gK + (size_t)(t + 1) * 64 * DIM, &Ks[cur ^ 1][tid * 8]);
            gld16(gV + (size_t)(t + 1) * 64,       &Vs[cur ^ 1][tid * 8]);
        }
        if (t < qblk) {
            ATTN_CORE(cur, t, false)
        } else if (t == qblk) {
            ATTN_CORE(cur, t, true)
        }
        VWAIT(0);
        BARRIER;
        cur ^= 1;
    }

    if (heavy) {
        // partial row index within the pair's 128 rows
        #pragma unroll
        for (int j = 0; j < 4; j++) {
            int lr = (w >> 2) * 64 + (w & 3) * 16 + lhi * 4 + j;
            size_t rbase = ((((size_t)half * 2 + b) * 16 + h) * 8 + (p - 8)) * 128 + lr;
            #pragma unroll
            for (int dt = 0; dt < 4; dt++)
                pb[rbase * 64 + dt * 16 + l15] = f2bf(octx[dt][j]);
            if (l15 == 0) sb[rbase] = octxS[j];
        }
    } else {
        #pragma unroll
        for (int j = 0; j < 4; j++) {
            float inv = 1.0f / octxS[j];
            #pragma unroll
            for (int dt = 0; dt < 4; dt++) {
                Ctx[((size_t)b * SEQ + qw + lhi * 4 + j) * DIM + h * HD + dt * 16 + l15] =
                    f2bf(octx[dt][j] * inv);
            }
        }
    }
}

// ---------------- combine heavy-pair partials -> Ctx -----------------------
// 32768 rows (2b x 16h x 8p x 128lr), one thread per row.
__global__ __launch_bounds__(256) void combine_kernel(
    const unsigned short* __restrict__ pb,
    const float* __restrict__ sb,
    unsigned short* __restrict__ Ctx)
{
    int row = blockIdx.x * 256 + threadIdx.x;   // 0..32767 = [b][h][pidx][lr]
    int lr   = row & 127;
    int pidx = (row >> 7) & 7;
    int h    = (row >> 10) & 15;
    int b    = row >> 14;
    float inv = 1.0f / (sb[row] + sb[row + 32768]);
    int q = (pidx + 8) * 128 + lr;
    const unsigned short* pA = pb + (size_t)row * 64;
    const unsigned short* pB = pA + (size_t)32768 * 64;
    unsigned short* out = Ctx + ((size_t)b * SEQ + q) * DIM + h * HD;
    #pragma unroll
    for (int c = 0; c < 64; c += 8) {
        ushort4 o0, o1;
        o0.x = f2bf((bf2f(pA[c + 0]) + bf2f(pB[c + 0])) * inv);
        o0.y = f2bf((bf2f(pA[c + 1]) + bf2f(pB[c + 1])) * inv);
        o0.z = f2bf((bf2f(pA[c + 2]) + bf2f(pB[c + 2])) * inv);
        o0.w = f2bf((bf2f(pA[c + 3]) + bf2f(pB[c + 3])) * inv);
        o1.x = f2bf((bf2f(pA[c + 4]) + bf2f(pB[c + 4])) * inv);
        o1.y = f2bf((bf2f(pA[c + 5]) + bf2f(pB[c + 5])) * inv);
        o1.z = f2bf((bf2f(pA[c + 6]) + bf2f(pB[c + 6])) * inv);
        o1.w = f2bf((bf2f(pA[c + 7]) + bf2f(pB[c + 7])) * inv);
        *(ushort4*)(out + c)     = o0;
        *(ushort4*)(out + c + 4) = o1;
    }
}

extern "C" void kernel_launch(void* const* d_in, const int* in_sizes, int n_in,
                              void* d_out, int out_size, void* d_ws, size_t ws_size,
                              hipStream_t stream) {
    const float* x  = (const float*)d_in[0];
    const float* Wq = (const float*)d_in[1];
    const float* Wk = (const float*)d_in[2];
    const float* Wv = (const float*)d_in[3];
    const float* Wo = (const float*)d_in[4];
    const float* bo = (const float*)d_in[5];

    char* ws = (char*)d_ws;
    unsigned short* xb   = (unsigned short*)(ws + 0 * MB);   // dead after qkv
    unsigned short* Wqb  = (unsigned short*)(ws + 8 * MB);   // dead after qkv
    unsigned short* Wkb  = (unsigned short*)(ws + 10 * MB);
    unsigned short* Wvb  = (unsigned short*)(ws + 12 * MB);
    unsigned short* Wob  = (unsigned short*)(ws + 14 * MB);  // live until o_gemm
    unsigned short* Qb   = (unsigned short*)(ws + 16 * MB);
    unsigned short* Kbf  = (unsigned short*)(ws + 24 * MB);
    unsigned short* Vtb  = (unsigned short*)(ws + 32 * MB);
    unsigned short* ctxb = (unsigned short*)(ws + 40 * MB);
    // attn partials overlay the dead xb/Wqb regions:
    unsigned short* pb   = (unsigned short*)(ws + 0 * MB);   // 8 MB bf16 partials
    float*          sbuf = (float*)(ws + 8 * MB);            // 256 KB f32 sums

    f2all_kernel<<<dim3(1024, 5), 256, 0, stream>>>(x, Wq, Wk, Wv, Wo,
                                                    xb, Wqb, Wkb, Wvb, Wob);

    qkv_gemm<<<768, 256, 0, stream>>>(xb, Wqb, Wkb, Wvb, Qb, Kbf, Vtb);

    attn_kernel<<<768, 512, 0, stream>>>(Qb, Kbf, Vtb, ctxb, pb, sbuf);

    combine_kernel<<<128, 256, 0, stream>>>(pb, sbuf, ctxb);

    o_gemm<<<1024, 256, 0, stream>>>(ctxb, Wob, (float*)d_out, bo);
}

// Round 22
// 108.271 us; speedup vs baseline: 1.0900x; 1.0900x over previous
//
#include <hip/hip_runtime.h>
#include <hip/hip_bf16.h>

#define DIM 1024
#define NHEADS 16
#define HD 64
#define SEQ 2048
#define BATCH 2
#define MROWS (BATCH * SEQ)   // 4096
#define MB (1024u * 1024u)
#define NT (SEQ / 64)         // 32 q-tiles

typedef __bf16 bf16x8 __attribute__((ext_vector_type(8)));
typedef float f32x4 __attribute__((ext_vector_type(4)));
typedef short short8 __attribute__((ext_vector_type(8)));

#define SCQ (0.125f * 1.44269504f)   // 1/sqrt(64) * log2(e), folded into Q

__device__ __forceinline__ unsigned short f2bf(float f) {
    union { float f; unsigned u; } v; v.f = f;
    unsigned r = v.u + 0x7fffu + ((v.u >> 16) & 1u);
    return (unsigned short)(r >> 16);
}
__device__ __forceinline__ unsigned cvtpk(float lo, float hi) {
    unsigned r;
    asm("v_cvt_pk_bf16_f32 %0, %1, %2" : "=v"(r) : "v"(lo), "v"(hi));
    return r;
}

// async global->LDS, 16B per lane; LDS dest = wave-uniform base + lane*16
__device__ __forceinline__ void gld16(const unsigned short* g, unsigned short* l) {
    __builtin_amdgcn_global_load_lds(
        (const __attribute__((address_space(1))) void*)g,
        (__attribute__((address_space(3))) void*)l, 16, 0, 0);
}

#define VWAIT(n) asm volatile("s_waitcnt vmcnt(" #n ")" ::: "memory")
#define BARRIER  do { __builtin_amdgcn_s_barrier(); __builtin_amdgcn_sched_barrier(0); } while (0)

// ---------------- fused fp32 -> bf16 conversion (x + 4 weights) ------------
__global__ __launch_bounds__(256) void f2all_kernel(
    const float* __restrict__ x,
    const float* __restrict__ w0, const float* __restrict__ w1,
    const float* __restrict__ w2, const float* __restrict__ w3,
    unsigned short* __restrict__ xb,
    unsigned short* __restrict__ o0, unsigned short* __restrict__ o1,
    unsigned short* __restrict__ o2, unsigned short* __restrict__ o3)
{
    const float* in; unsigned short* out; int n4;
    switch (blockIdx.y) {
        case 0: in = x;  out = xb; n4 = (MROWS * DIM) / 4; break;
        case 1: in = w0; out = o0; n4 = (DIM * DIM) / 4;   break;
        case 2: in = w1; out = o1; n4 = (DIM * DIM) / 4;   break;
        case 3: in = w2; out = o2; n4 = (DIM * DIM) / 4;   break;
        default: in = w3; out = o3; n4 = (DIM * DIM) / 4;  break;
    }
    for (int i = blockIdx.x * 256 + threadIdx.x; i < n4; i += 1024 * 256) {
        float4 v = ((const float4*)in)[i];
        ushort4 o;
        o.x = f2bf(v.x); o.y = f2bf(v.y); o.z = f2bf(v.z); o.w = f2bf(v.w);
        ((ushort4*)out)[i] = o;
    }
}

// ========== GEMM mainloop: 3-buffer, 2-deep counted-vmcnt pipeline ==========
// (proven: 128x128 tile, BK=32, 256 thr, 48KB LDS -> 3 blocks/CU.
//  Swizzle c ^ ((row>>1)&3): 0 bank conflicts. Occupancy-bound optimum.)

#define GEMM_VARS(Aptr, Bptr)                                                  \
    __shared__ unsigned short As[3][128 * 32];                                 \
    __shared__ unsigned short Bs[3][128 * 32];                                 \
    const int tid  = threadIdx.x;                                              \
    const int lane = tid & 63;                                                 \
    const int wid  = tid >> 6;                                                 \
    const int wrow = wid >> 1, wcol = wid & 1;                                 \
    const int l15  = lane & 15;                                                \
    const int lhi  = lane >> 4;                                                \
    f32x4 acc[4][4] = {};                                                      \
    const int r0s = tid >> 2;                                                  \
    const int c0s = (tid & 3) ^ ((r0s >> 1) & 3);                              \
    const int r1s = (tid + 256) >> 2;                                          \
    const int c1s = (tid & 3) ^ ((r1s >> 1) & 3);                              \
    const unsigned short* gA0 = (Aptr) + (size_t)(row0 + r0s) * DIM + c0s * 8; \
    const unsigned short* gA1 = (Aptr) + (size_t)(row0 + r1s) * DIM + c1s * 8; \
    const unsigned short* gB0 = (Bptr) + (size_t)(col0 + r0s) * DIM + c0s * 8; \
    const unsigned short* gB1 = (Bptr) + (size_t)(col0 + r1s) * DIM + c1s * 8;

#define GEMM_STAGE(bi, kofs)                                                   \
    gld16(gA0 + (kofs), &As[bi][tid * 8]);                                     \
    gld16(gA1 + (kofs), &As[bi][(tid + 256) * 8]);                             \
    gld16(gB0 + (kofs), &Bs[bi][tid * 8]);                                     \
    gld16(gB1 + (kofs), &Bs[bi][(tid + 256) * 8]);

#define GEMM_COMPUTE(bi)                                                       \
    {   const unsigned short* Ac = &As[bi][0];                                 \
        const unsigned short* Bc = &Bs[bi][0];                                 \
        bf16x8 af[4], bfr[4];                                                  \
        _Pragma("unroll")                                                      \
        for (int m = 0; m < 4; m++) {                                          \
            int r = wrow * 64 + m * 16 + l15;                                  \
            int c = lhi ^ ((r >> 1) & 3);                                      \
            af[m] = *(const bf16x8*)&Ac[r * 32 + c * 8];                       \
        }                                                                      \
        _Pragma("unroll")                                                      \
        for (int n = 0; n < 4; n++) {                                          \
            int r = wcol * 64 + n * 16 + l15;                                  \
            int c = lhi ^ ((r >> 1) & 3);                                      \
            bfr[n] = *(const bf16x8*)&Bc[r * 32 + c * 8];                      \
        }                                                                      \
        __builtin_amdgcn_s_setprio(1);                                         \
        _Pragma("unroll")                                                      \
        for (int m = 0; m < 4; m++)                                            \
            _Pragma("unroll")                                                  \
            for (int n = 0; n < 4; n++)                                        \
                acc[m][n] = __builtin_amdgcn_mfma_f32_16x16x32_bf16(           \
                    af[m], bfr[n], acc[m][n], 0, 0, 0);                        \
        __builtin_amdgcn_s_setprio(0);                                         \
    }

#define GEMM_PIPELINE()                                                        \
    GEMM_STAGE(0, 0)                                                           \
    GEMM_STAGE(1, 32)                                                          \
    int bi = 0;                                                                \
    for (int k0 = 0; k0 + 96 <= DIM; k0 += 32) {                               \
        VWAIT(4);                                                              \
        BARRIER;                                                               \
        int b2 = bi + 2; if (b2 >= 3) b2 -= 3;                                 \
        GEMM_STAGE(b2, k0 + 64)                                                \
        GEMM_COMPUTE(bi)                                                       \
        bi = (bi + 1 == 3) ? 0 : bi + 1;                                       \
    }                                                                          \
    VWAIT(4);                                                                  \
    BARRIER;                                                                   \
    GEMM_COMPUTE(bi)                                                           \
    bi = (bi + 1 == 3) ? 0 : bi + 1;                                           \
    VWAIT(0);                                                                  \
    BARRIER;                                                                   \
    GEMM_COMPUTE(bi)

// ---------------- fused QKV GEMM (768 blocks, r10-proven XCD swizzle) ------
__global__ __launch_bounds__(256) void qkv_gemm(
    const unsigned short* __restrict__ A,
    const unsigned short* __restrict__ Wqb,
    const unsigned short* __restrict__ Wkb,
    const unsigned short* __restrict__ Wvb,
    unsigned short* __restrict__ Qb,
    unsigned short* __restrict__ Kbf,
    unsigned short* __restrict__ Vtb)
{
    const int lb  = ((int)blockIdx.x & 7) * 96 + ((int)blockIdx.x >> 3);
    const int xx  = lb % 24;
    const int yy  = lb / 24;
    const int sel = xx >> 3;
    const unsigned short* Bw = (sel == 0) ? Wqb : ((sel == 1) ? Wkb : Wvb);
    const int row0 = yy * 128;
    const int col0 = (xx & 7) * 128;

    GEMM_VARS(A, Bw)
    GEMM_PIPELINE()

    const int cr = lhi * 4;
    unsigned short* outRM = (sel == 0) ? Qb : Kbf;
    #pragma unroll
    for (int m = 0; m < 4; m++) {
        #pragma unroll
        for (int n = 0; n < 4; n++) {
            int gc = col0 + wcol * 64 + n * 16 + l15;
            if (sel < 2) {
                #pragma unroll
                for (int j2 = 0; j2 < 4; j2++) {
                    int gr = row0 + wrow * 64 + m * 16 + cr + j2;
                    float v = acc[m][n][j2];
                    if (sel == 0) v *= SCQ;   // fold softmax scale + log2e into Q
                    outRM[(size_t)gr * DIM + gc] = f2bf(v);
                }
            } else {
                // Vt scatter: 4 consecutive s -> one 8B store (s0 % 4 == 0,
                // same batch block since gr base is 4-aligned)
                int gr0 = row0 + wrow * 64 + m * 16 + cr;
                int bb = gr0 >> 11, s0 = gr0 & 2047;
                int hh = gc >> 6,  d = gc & 63;
                ushort4 pv4;
                pv4.x = f2bf(acc[m][n][0]);
                pv4.y = f2bf(acc[m][n][1]);
                pv4.z = f2bf(acc[m][n][2]);
                pv4.w = f2bf(acc[m][n][3]);
                *(ushort4*)&Vtb[(((size_t)bb * NHEADS + hh) * HD + d) * SEQ + s0] = pv4;
            }
        }
    }
}

// ------------- O-projection GEMM: 64x64 tile, 1024 blocks (4/CU) -----------
__global__ __launch_bounds__(256) void o_gemm(
    const unsigned short* __restrict__ A,
    const unsigned short* __restrict__ Bw,
    float* __restrict__ Cp,
    const float* __restrict__ bias)
{
    __shared__ unsigned short As[3][64 * 32];    // 4KB per buf
    __shared__ unsigned short Bs[3][64 * 32];    // 4KB per buf

    const int lb  = ((int)blockIdx.x & 7) * 128 + ((int)blockIdx.x >> 3);
    const int xx  = lb % 16;
    const int yy  = lb / 16;
    const int row0 = yy * 64;
    const int col0 = xx * 64;

    const int tid  = threadIdx.x;
    const int lane = tid & 63;
    const int wid  = tid >> 6;
    const int wrow = wid >> 1, wcol = wid & 1;   // wave tile: 32 rows x 32 cols
    const int l15  = lane & 15;
    const int lhi  = lane >> 4;
    f32x4 acc[2][2] = {};

    const int r0s = tid >> 2;                      // 0..63
    const int c0s = (tid & 3) ^ ((r0s >> 1) & 3);
    const unsigned short* gA0 = A  + (size_t)(row0 + r0s) * DIM + c0s * 8;
    const unsigned short* gB0 = Bw + (size_t)(col0 + r0s) * DIM + c0s * 8;

#define OSTAGE(bi, kofs)                                     \
    gld16(gA0 + (kofs), &As[bi][tid * 8]);                   \
    gld16(gB0 + (kofs), &Bs[bi][tid * 8]);

#define OCOMPUTE(bi)                                                           \
    {   const unsigned short* Ac = &As[bi][0];                                 \
        const unsigned short* Bc = &Bs[bi][0];                                 \
        bf16x8 af[2], bfr[2];                                                  \
        _Pragma("unroll")                                                      \
        for (int m = 0; m < 2; m++) {                                          \
            int r = wrow * 32 + m * 16 + l15;                                  \
            int c = lhi ^ ((r >> 1) & 3);                                      \
            af[m] = *(const bf16x8*)&Ac[r * 32 + c * 8];                       \
        }                                                                      \
        _Pragma("unroll")                                                      \
        for (int n = 0; n < 2; n++) {                                          \
            int r = wcol * 32 + n * 16 + l15;                                  \
            int c = lhi ^ ((r >> 1) & 3);                                      \
            bfr[n] = *(const bf16x8*)&Bc[r * 32 + c * 8];                      \
        }                                                                      \
        __builtin_amdgcn_s_setprio(1);                                         \
        _Pragma("unroll")                                                      \
        for (int m = 0; m < 2; m++)                                            \
            _Pragma("unroll")                                                  \
            for (int n = 0; n < 2; n++)                                        \
                acc[m][n] = __builtin_amdgcn_mfma_f32_16x16x32_bf16(           \
                    af[m], bfr[n], acc[m][n], 0, 0, 0);                        \
        __builtin_amdgcn_s_setprio(0);                                         \
    }

    OSTAGE(0, 0)
    OSTAGE(1, 32)
    int bi = 0;
    for (int k0 = 0; k0 + 96 <= DIM; k0 += 32) {
        VWAIT(2);
        BARRIER;
        int b2 = bi + 2; if (b2 >= 3) b2 -= 3;
        OSTAGE(b2, k0 + 64)
        OCOMPUTE(bi)
        bi = (bi + 1 == 3) ? 0 : bi + 1;
    }
    VWAIT(2);
    BARRIER;
    OCOMPUTE(bi)
    bi = (bi + 1 == 3) ? 0 : bi + 1;
    VWAIT(0);
    BARRIER;
    OCOMPUTE(bi)
#undef OSTAGE
#undef OCOMPUTE

    const int cr = lhi * 4;
    #pragma unroll
    for (int m = 0; m < 2; m++) {
        #pragma unroll
        for (int n = 0; n < 2; n++) {
            #pragma unroll
            for (int j = 0; j < 4; j++) {
                int gr = row0 + wrow * 32 + m * 16 + cr + j;
                int gc = col0 + wcol * 32 + n * 16 + l15;
                Cp[(size_t)gr * DIM + gc] = acc[m][n][j] + bias[gc];
            }
        }
    }
}

// ---------------- causal flash attention (adjacent-pair balancing) ---------
// 512 thr (8 waves). Waves 0-3: q-tile 2p; waves 4-7: q-tile 2p+1. Heavy
// blocks (large p) dispatched first. Diagonal tile PEELED (interior tiles
// mask-free); V-fragment reads hoisted over the P write->read gap.
// 2-BUFFER K/V staging (50KB LDS -> 3 blocks/CU).
#define ATTN_CORE(bi, t, MASKED)                                               \
    {   const unsigned short* Kc = &Ks[bi][0];                                 \
        const unsigned short* Vc = &Vs[bi][0];                                 \
        f32x4 sacc[4] = {};                                                    \
        __builtin_amdgcn_s_setprio(1);                                         \
        _Pragma("unroll")                                                      \
        for (int ks = 0; ks < 2; ++ks) {                                       \
            bf16x8 bq = ks ? aq1 : aq0;                                        \
            _Pragma("unroll")                                                  \
            for (int nt = 0; nt < 4; nt++) {                                   \
                int r = nt * 16 + l15;                                         \
                int c = (ks * 4 + lhi) ^ (r & 7);                              \
                bf16x8 ak = *(const bf16x8*)&Kc[r * 64 + c * 8];               \
                sacc[nt] = __builtin_amdgcn_mfma_f32_16x16x32_bf16(            \
                    ak, bq, sacc[nt], 0, 0, 0);                                \
            }                                                                  \
        }                                                                      \
        __builtin_amdgcn_s_setprio(0);                                         \
        _Pragma("unroll")                                                      \
        for (int nt = 0; nt < 4; nt++) {                                       \
            float pv[4];                                                       \
            _Pragma("unroll")                                                  \
            for (int j = 0; j < 4; j++) {                                      \
                if (MASKED && (nt * 16 + lhi * 4 + j > (w & 3) * 16 + l15))    \
                    pv[j] = 0.f;                                               \
                else                                                           \
                    pv[j] = exp2f(sacc[nt][j]);                                \
            }                                                                  \
            *(uint2*)&Ps[w][l15][nt * 16 + lhi * 4] =                          \
                make_uint2(cvtpk(pv[0], pv[1]), cvtpk(pv[2], pv[3]));          \
        }                                                                      \
        /* independent V-frag loads fill the P write->read latency gap */      \
        bf16x8 bv[2][4];                                                       \
        _Pragma("unroll")                                                      \
        for (int ks = 0; ks < 2; ++ks)                                         \
            _Pragma("unroll")                                                  \
            for (int dt = 0; dt < 4; dt++) {                                   \
                int r = dt * 16 + l15;                                         \
                int c = (ks * 4 + lhi) ^ (r & 7);                              \
                bv[ks][dt] = *(const bf16x8*)&Vc[r * 64 + c * 8];              \
            }                                                                  \
        _Pragma("unroll")                                                      \
        for (int ks = 0; ks < 2; ++ks) {                                       \
            bf16x8 ap = *(const bf16x8*)&Ps[w][l15][ks * 32 + lhi * 8];        \
            __builtin_amdgcn_s_setprio(1);                                     \
            _Pragma("unroll")                                                  \
            for (int dt = 0; dt < 4; dt++)                                     \
                octx[dt] = __builtin_amdgcn_mfma_f32_16x16x32_bf16(            \
                    ap, bv[ks][dt], octx[dt], 0, 0, 0);                        \
            octxS = __builtin_amdgcn_mfma_f32_16x16x32_bf16(ap, vones, octxS, 0, 0, 0); \
            __builtin_amdgcn_s_setprio(0);                                     \
        }                                                                      \
    }

__global__ __launch_bounds__(512) void attn_kernel(
    const unsigned short* __restrict__ Q,
    const unsigned short* __restrict__ Kb,
    const unsigned short* __restrict__ Vt,
    unsigned short* __restrict__ Ctx)
{
    __shared__ unsigned short Ks[2][64 * 64];   // 8KB each
    __shared__ unsigned short Vs[2][64 * 64];
    __shared__ unsigned short Ps[8][16][72];    // 18KB

    const int tid  = threadIdx.x;
    const int lane = tid & 63;
    const int w    = tid >> 6;        // 0..7
    // dispatch map: blocks 0-255 heavy (p=15..8), 256-511 light (p=7..0)
    const int bid  = (int)blockIdx.x;
    const int half = bid >> 8;
    const int idx  = bid & 255;
    const int h    = idx & 15;
    const int b    = (idx >> 4) & 1;
    const int slot = idx >> 5;        // 0..7
    const int p    = half ? slot : (15 - slot);
    const int l15  = lane & 15;
    const int lhi  = lane >> 4;

    const int qblk   = 2 * p + (w >> 2);     // waves 0-3: 2p, waves 4-7: 2p+1
    const int qw     = qblk * 64 + (w & 3) * 16;
    const int ntiles = 2 * p + 2;            // KV tiles 0..2p+1

    const size_t qrow = ((size_t)b * SEQ + qw + l15) * DIM + h * HD;
    bf16x8 aq0 = *(const bf16x8*)(Q + qrow + lhi * 8);
    bf16x8 aq1 = *(const bf16x8*)(Q + qrow + 32 + lhi * 8);

    const int srow = tid >> 3;                   // 0..63
    const int sc16 = (tid & 7) ^ (srow & 7);
    const unsigned short* gK = Kb + ((size_t)b * SEQ + srow) * DIM + h * HD + sc16 * 8;
    const unsigned short* gV = Vt + (((size_t)b * NHEADS + h) * HD + srow) * SEQ + sc16 * 8;

    bf16x8 vones;
    #pragma unroll
    for (int i = 0; i < 8; i++) vones[i] = (__bf16)1.0f;

    f32x4 octx[4] = {};
    f32x4 octxS = {};

    gld16(gK, &Ks[0][tid * 8]);
    gld16(gV, &Vs[0][tid * 8]);
    VWAIT(0);
    BARRIER;

    int cur = 0;
    for (int t = 0; t < ntiles; ++t) {
        if (t + 1 < ntiles) {
            gld16(gK + (size_t)(t + 1) * 64 * DIM, &Ks[cur ^ 1][tid * 8]);
            gld16(gV + (size_t)(t + 1) * 64,       &Vs[cur ^ 1][tid * 8]);
        }
        if (t < qblk) {
            ATTN_CORE(cur, t, false)
        } else if (t == qblk) {
            ATTN_CORE(cur, t, true)
        }
        VWAIT(0);     // t+1 landed (drain hidden under the compute above)
        BARRIER;      // all waves done reading buf cur -> safe to overwrite
        cur ^= 1;
    }

    #pragma unroll
    for (int j = 0; j < 4; j++) {
        float inv = 1.0f / octxS[j];
        #pragma unroll
        for (int dt = 0; dt < 4; dt++) {
            Ctx[((size_t)b * SEQ + qw + lhi * 4 + j) * DIM + h * HD + dt * 16 + l15] =
                f2bf(octx[dt][j] * inv);
        }
    }
}

extern "C" void kernel_launch(void* const* d_in, const int* in_sizes, int n_in,
                              void* d_out, int out_size, void* d_ws, size_t ws_size,
                              hipStream_t stream) {
    const float* x  = (const float*)d_in[0];
    const float* Wq = (const float*)d_in[1];
    const float* Wk = (const float*)d_in[2];
    const float* Wv = (const float*)d_in[3];
    const float* Wo = (const float*)d_in[4];
    const float* bo = (const float*)d_in[5];

    char* ws = (char*)d_ws;
    unsigned short* xb   = (unsigned short*)(ws + 0 * MB);
    unsigned short* Wqb  = (unsigned short*)(ws + 8 * MB);
    unsigned short* Wkb  = (unsigned short*)(ws + 10 * MB);
    unsigned short* Wvb  = (unsigned short*)(ws + 12 * MB);
    unsigned short* Wob  = (unsigned short*)(ws + 14 * MB);
    unsigned short* Qb   = (unsigned short*)(ws + 16 * MB);
    unsigned short* Kbf  = (unsigned short*)(ws + 24 * MB);
    unsigned short* Vtb  = (unsigned short*)(ws + 32 * MB);
    unsigned short* ctxb = (unsigned short*)(ws + 40 * MB);

    f2all_kernel<<<dim3(1024, 5), 256, 0, stream>>>(x, Wq, Wk, Wv, Wo,
                                                    xb, Wqb, Wkb, Wvb, Wob);

    qkv_gemm<<<768, 256, 0, stream>>>(xb, Wqb, Wkb, Wvb, Qb, Kbf, Vtb);

    attn_kernel<<<512, 512, 0, stream>>>(Qb, Kbf, Vtb, ctxb);

    o_gemm<<<1024, 256, 0, stream>>>(ctxb, Wob, (float*)d_out, bo);
}